// Round 16
// baseline (586.596 us; speedup 1.0000x reference)
//
#include <hip/hip_runtime.h>
#include <math.h>

// ---------- problem constants ----------
constexpr int SEQ_T = 72;
constexpr int FDIM  = 64;
constexpr int UNITS = 256;
constexpr int U4    = 1024;
constexpr int BATCH = 4096;
constexpr int NKC   = 10;          // k-chunks of 32 (x: kc0-1, h: kc2-9)
constexpr float LOG2E = 1.4426950408889634f;

// Partition: 256 blocks = 64 row-groups (64 rows) x 4 unit-quarters (64 units x 4 gates).
// NEW: each block's 64 rows split into TWO independent 32-row SETS, phase-interleaved
// so one set's L3 exchange + flag wait hides under the other set's compute.
// Weights per block: 96 KB LDS (kc0-5) + 64 VGPR/lane (kc6-9) — r15-proven split.

// LDS (bytes): A [2 set][10 kc][2 m][64][8]sh = 40960 ; WL 98304 ; hst [2 set][2][2][64][8]sh = 8192
constexpr int LDS_BYTES = 40960 + 98304 + 8192;   // 147456

using bf16x8 = __attribute__((ext_vector_type(8))) short;
using bf16x4 = __attribute__((ext_vector_type(4))) short;
using f32x4  = __attribute__((ext_vector_type(4))) float;
using ull    = unsigned long long;

__device__ __forceinline__ float sig2(float x) {           // z pre-scaled by log2e
    return __builtin_amdgcn_rcpf(1.0f + exp2f(-x));
}
__device__ __forceinline__ float tanh2(float x) {           // arg pre-scaled by log2e
    float t = 1.0f - 2.0f * __builtin_amdgcn_rcpf(exp2f(2.0f * fabsf(x)) + 1.0f);
    return copysignf(t, x);
}
__device__ __forceinline__ float tanhc(float x) {           // unscaled arg (cell state)
    float t = 1.0f - 2.0f * __builtin_amdgcn_rcpf(exp2f(2.0f * LOG2E * fabsf(x)) + 1.0f);
    return copysignf(t, x);
}
__device__ __forceinline__ unsigned short f2bf(float f) {
    union { float f; unsigned u; } v; v.f = f;
    unsigned r = (v.u + 0x7FFFu + ((v.u >> 16) & 1u)) >> 16;   // RNE
    return (unsigned short)r;
}

// ---------- prep: z-weights (PRE-SCALED by log2e), blob idx = (((ub*10+kc)*4+ug)*4+g)*64+l ----------
__global__ void prep_wblob(const float* __restrict__ W, const float* __restrict__ U,
                           unsigned short* __restrict__ Wblob) {
    int id = blockIdx.x * 256 + threadIdx.x;    // 40960
    int l    = id & 63;
    int g    = (id >> 6) & 3;
    int ug   = (id >> 8) & 3;
    int rest = id >> 10;                         // ub*10 + kc
    int kc   = rest % 10, ub = rest / 10;
    int col  = g * 256 + ub * 64 + ug * 16 + (l & 15);
    int kb   = kc * 32 + (l >> 4) * 8;
    bf16x8 v;
    #pragma unroll
    for (int e = 0; e < 8; ++e) {
        int k = kb + e;
        float f = (k < FDIM) ? W[(size_t)k * U4 + col] : U[(size_t)(k - FDIM) * U4 + col];
        v[e] = (short)f2bf(f * LOG2E);
    }
    *reinterpret_cast<bf16x8*>(Wblob + (size_t)id * 8) = v;
}

// ---------- prep: dense weights (unscaled), blob idx = (ft*8 + kcd)*64 + l ----------
__global__ void prep_wdblob(const float* __restrict__ Wd, unsigned short* __restrict__ Wdblob) {
    int id = blockIdx.x * 256 + threadIdx.x;    // 2048
    int l   = id & 63;
    int kcd = (id >> 6) & 7;
    int ft  = id >> 9;
    int f   = ft * 16 + (l & 15);
    int kb  = kcd * 32 + (l >> 4) * 8;
    bf16x8 v;
    #pragma unroll
    for (int e = 0; e < 8; ++e)
        v[e] = (short)f2bf(Wd[(size_t)(kb + e) * FDIM + f]);
    *reinterpret_cast<bf16x8*>(Wdblob + (size_t)id * 8) = v;
}

__device__ __forceinline__ ull agload(const ull* p) {
    return __hip_atomic_load(p, __ATOMIC_RELAXED, __HIP_MEMORY_SCOPE_AGENT);
}
__device__ __forceinline__ void agstore(ull* p, ull v) {
    __hip_atomic_store(p, v, __ATOMIC_RELAXED, __HIP_MEMORY_SCOPE_AGENT);
}

// hbuf geometry (ull units): [2 parity][64 rg][2 set][2048]
constexpr size_t PSTR = (size_t)64 * 2 * 2048;

// ======== one set's full step phase (S is a literal 0/1 -> compile-time) ========
#define SET_PHASE(S, XQ, CREG)                                                     \
{                                                                                  \
    unsigned short* Aset = A_s + (S) * 10240;                                      \
    if (t > 0) {                                                                   \
        const unsigned* fb = flags + rg * 32 + (S) * 4;                            \
        for (;;) {                                                                 \
            unsigned f0 = __hip_atomic_load(fb + 0, __ATOMIC_RELAXED, __HIP_MEMORY_SCOPE_AGENT); \
            unsigned f1 = __hip_atomic_load(fb + 1, __ATOMIC_RELAXED, __HIP_MEMORY_SCOPE_AGENT); \
            unsigned f2 = __hip_atomic_load(fb + 2, __ATOMIC_RELAXED, __HIP_MEMORY_SCOPE_AGENT); \
            unsigned f3 = __hip_atomic_load(fb + 3, __ATOMIC_RELAXED, __HIP_MEMORY_SCOPE_AGENT); \
            if (f0 >= (unsigned)t && f1 >= (unsigned)t &&                          \
                f2 >= (unsigned)t && f3 >= (unsigned)t) break;                     \
            __builtin_amdgcn_s_sleep(1);                                           \
        }                                                                          \
    }                                                                              \
    __builtin_amdgcn_sched_barrier(0);                                             \
    ull* Ah = (ull*)(Aset + 2048);                                                 \
    if (t == 0) {                                                                  \
        _Pragma("unroll")                                                          \
        for (int i = 0; i < 4; ++i) Ah[i * 512 + tid] = 0ull;                      \
    } else {                                                                       \
        const ull* src = hb_ull + (size_t)p * PSTR + ((size_t)rg * 2 + (S)) * 2048;\
        ull v0 = agload(src + 0 * 512 + tid);                                      \
        ull v1 = agload(src + 1 * 512 + tid);                                      \
        ull v2 = agload(src + 2 * 512 + tid);                                      \
        ull v3 = agload(src + 3 * 512 + tid);                                      \
        Ah[0 * 512 + tid] = v0; Ah[1 * 512 + tid] = v1;                            \
        Ah[2 * 512 + tid] = v2; Ah[3 * 512 + tid] = v3;                            \
    }                                                                              \
    if (t < SEQ_T) {                                                               \
        bf16x4 pk;                                                                 \
        pk[0] = (short)f2bf(XQ.x); pk[1] = (short)f2bf(XQ.y);                      \
        pk[2] = (short)f2bf(XQ.z); pk[3] = (short)f2bf(XQ.w);                      \
        *reinterpret_cast<bf16x4*>(Aset + ((xkc * 2 + xm) * 64 + xlnb) * 8 + xel) = pk; \
        __syncthreads();                                                           \
        if (t + 1 < SEQ_T)                                                         \
            XQ = *reinterpret_cast<const float4*>(                                 \
                inputs + ((size_t)(bb + (S) * 32 + xr) * SEQ_T + (t + 1)) * FDIM + xc4); \
    } else {                                                                       \
        __syncthreads();                                                           \
        const int sstep = t - SEQ_T;                                               \
        f32x4 accp = {0.f, 0.f, 0.f, 0.f};                                         \
        _Pragma("unroll")                                                          \
        for (int kcd = 0; kcd < 8; ++kcd) {                                        \
            bf16x8 a = *reinterpret_cast<const bf16x8*>(                           \
                Aset + (((2 + kcd) * 2 + m) * 64 + lane) * 8);                     \
            bf16x8 bw = *reinterpret_cast<const bf16x8*>(                          \
                Wdblob + (size_t)((((w & 3) * 8 + kcd) * 64) + lane) * 8);         \
            accp = __builtin_amdgcn_mfma_f32_16x16x32_bf16(a, bw, accp, 0, 0, 0);  \
        }                                                                          \
        _Pragma("unroll")                                                          \
        for (int j = 0; j < 4; ++j) {                                              \
            int rr = m * 16 + hi4 * 4 + j;                                         \
            float v = accp[j] + bdv;                                               \
            if (ub == 0)                                                           \
                out[((size_t)(bb + (S) * 32 + rr) * out_steps + sstep) * FDIM + fcol] = v; \
            Aset[((fkc * 2 + m) * 64 + ((rr & 15) | flsh)) * 8 + fel] = f2bf(v);   \
        }                                                                          \
        if (t < tmax) __syncthreads();                                             \
    }                                                                              \
    if (t < tmax) {                                                                \
        f32x4 acc[4];                                                              \
        _Pragma("unroll")                                                          \
        for (int g = 0; g < 4; ++g) acc[g] = (f32x4){0.f, 0.f, 0.f, 0.f};          \
        _Pragma("unroll")                                                          \
        for (int kc = 0; kc < NKC; ++kc) {                                         \
            bf16x8 a = *reinterpret_cast<const bf16x8*>(                           \
                Aset + ((kc * 2 + m) * 64 + lane) * 8);                            \
            _Pragma("unroll")                                                      \
            for (int g = 0; g < 4; ++g) {                                          \
                bf16x8 bw = (kc < 6)                                               \
                    ? *reinterpret_cast<const bf16x8*>(                            \
                          WL + (((kc * 4 + ug) * 4 + g) * 64 + lane) * 8)          \
                    : Breg[kc - 6][g];                                             \
                acc[g] = __builtin_amdgcn_mfma_f32_16x16x32_bf16(a, bw, acc[g], 0, 0, 0); \
            }                                                                      \
        }                                                                          \
        _Pragma("unroll")                                                          \
        for (int j = 0; j < 4; ++j) {                                              \
            float zi = acc[0][j] + bz[0];                                          \
            float zf = acc[1][j] + bz[1];                                          \
            float zg = acc[2][j] + bz[2];                                          \
            float zo = acc[3][j] + bz[3];                                          \
            float ig = sig2(zi);                                                   \
            float fg = sig2(zf);                                                   \
            float og = sig2(zo);                                                   \
            float cn = fg * CREG[j] + ig * tanh2(zg);                              \
            CREG[j] = cn;                                                          \
            int rl = hi4 * 4 + j;                                                  \
            hst[(S) * 2048 + ((kcb * 2 + m) * 64 + (rl | lsh2)) * 8 + hel] = f2bf(og * tanhc(cn)); \
        }                                                                          \
        __syncthreads();                                                           \
        ull* dst = hb_ull + (size_t)(1 - p) * PSTR + ((size_t)rg * 2 + (S)) * 2048 + (size_t)ub * 512; \
        agstore(dst + tid, ((const ull*)(hst + (S) * 2048))[tid]);                 \
        __syncthreads();                                                           \
        if (tid == 0)                                                              \
            __hip_atomic_store(flags + rg * 32 + (S) * 4 + ub, (unsigned)(t + 1),  \
                               __ATOMIC_RELAXED, __HIP_MEMORY_SCOPE_AGENT);        \
    }                                                                              \
}

// ---------- persistent unit-split LSTM, 2 interleaved row-sets ----------
// grid 256 x 512 (8 waves). rg = blk & 63, ub = blk >> 6 (same-XCD groups).
// Wave w: ug = w&3 (16 units), m = w>>2 (16-row tile within a 32-row set).
__global__ __launch_bounds__(512, 1) void lstm_persistent(
    const float* __restrict__ inputs,          // [B][72][64] fp32
    const float* __restrict__ bias,            // [1024] fp32
    const unsigned short* __restrict__ Wblob,  // z-weight blobs (640 KB, pre-scaled)
    const unsigned short* __restrict__ Wdblob, // dense blobs (32 KB)
    const float* __restrict__ bd,              // [64] fp32
    unsigned short* __restrict__ hbuf,         // [2][64 rg][2 set][2048 ull] bf16
    unsigned int* __restrict__ flags,          // [64 rg x 32] (128B-spaced)
    float* __restrict__ out,                   // [B][out_steps][64] fp32
    int out_steps)
{
    extern __shared__ char smem[];
    unsigned short* A_s = (unsigned short*)smem;             // [2 set][10][2][64][8]
    unsigned short* WL  = (unsigned short*)(smem + 40960);   // [6][4][4][64][8]
    unsigned short* hst = (unsigned short*)(smem + 139264);  // [2 set][2][2][64][8]

    const int tid  = threadIdx.x;
    const int w    = tid >> 6, lane = tid & 63;
    const int l16  = lane & 15, hi4 = lane >> 4;
    const int blk  = blockIdx.x;
    const int rg   = blk & 63, ub = blk >> 6;
    const int bb   = rg * 64;
    const int ug   = w & 3;
    const int m    = w >> 2;                   // 16-row tile within set
    ull* hb_ull    = (ull*)hbuf;

    // ---- LDS weights kc0-5 (96 KB, once) ----
    {
        const unsigned short* src = Wblob + (size_t)(ub * 10) * 16 * 512;
        #pragma unroll
        for (int i = 0; i < 12; ++i) {
            int idx = (i * 512 + tid) * 8;
            *reinterpret_cast<bf16x8*>(WL + idx) =
                *reinterpret_cast<const bf16x8*>(src + idx);
        }
    }
    // ---- register weights kc6-9 (wave's ug slice): 64 VGPRs ----
    bf16x8 Breg[4][4];
    #pragma unroll
    for (int i = 0; i < 4; ++i)
        #pragma unroll
        for (int g = 0; g < 4; ++g)
            Breg[i][g] = *reinterpret_cast<const bf16x8*>(
                Wblob + ((size_t)(((ub * 10 + 6 + i) * 4 + ug) * 4 + g) * 64 + lane) * 8);

    const int uu = ub * 64 + ug * 16 + l16;
    float bz[4];
    #pragma unroll
    for (int g = 0; g < 4; ++g) bz[g] = bias[g * 256 + uu] * LOG2E;
    const float bdv = bd[(w & 3) * 16 + l16];

    // per-set cell state
    float c0[4] = {0.f, 0.f, 0.f, 0.f};
    float c1[4] = {0.f, 0.f, 0.f, 0.f};

    // x staging constants (per set: 32 rows x 64 cols, float4/thread)
    const int xr  = tid >> 4, xc4 = (tid & 15) * 4;
    const int xkc = xc4 >> 5, xm = xr >> 4;
    const int xlnb = (xr & 15) | (((xc4 & 31) >> 3) << 4);
    const int xel  = xc4 & 7;

    // dense-head constants
    const int fcol = (w & 3) * 16 + l16;
    const int fkc  = fcol >> 5;
    const int flsh = ((fcol & 31) >> 3) << 4;
    const int fel  = fcol & 7;

    // gate/hst constants
    const int kcb  = ug >> 1;
    const int lsh2 = ((ug & 1) * 2 + (l16 >> 3)) << 4;
    const int hel  = l16 & 7;

    const int tmax = SEQ_T + out_steps - 1;    // 95

    // x(0) prefetch, one float4 per set
    float4 xq0 = *reinterpret_cast<const float4*>(
        inputs + ((size_t)(bb + xr) * SEQ_T + 0) * FDIM + xc4);
    float4 xq1 = *reinterpret_cast<const float4*>(
        inputs + ((size_t)(bb + 32 + xr) * SEQ_T + 0) * FDIM + xc4);

    #pragma unroll 1
    for (int t = 0; ; ++t) {
        const int p = t & 1;
        SET_PHASE(0, xq0, c0)
        SET_PHASE(1, xq1, c1)
        if (t == tmax) break;
    }
}

extern "C" void kernel_launch(void* const* d_in, const int* in_sizes, int n_in,
                              void* d_out, int out_size, void* d_ws, size_t ws_size,
                              hipStream_t stream) {
    const float* inputs = (const float*)d_in[0];
    const float* W      = (const float*)d_in[1];
    const float* U      = (const float*)d_in[2];
    const float* b      = (const float*)d_in[3];
    const float* Wd     = (const float*)d_in[4];
    const float* bd     = (const float*)d_in[5];
    float* out = (float*)d_out;

    const int out_steps = out_size / (BATCH * FDIM);   // 24

    char* ws = (char*)d_ws;
    unsigned short* Wblob  = (unsigned short*)(ws);               // 640 KB
    unsigned short* Wdblob = (unsigned short*)(ws + (1u << 20));  // 32 KB
    unsigned short* hbuf   = (unsigned short*)(ws + (2u << 20));  // 4 MB
    unsigned int*   flags  = (unsigned int*)(ws + (6u << 20));    // 64 x 128 B

    prep_wblob<<<160, 256, 0, stream>>>(W, U, Wblob);
    prep_wdblob<<<8, 256, 0, stream>>>(Wd, Wdblob);
    hipMemsetAsync(flags, 0, 64 * 128, stream);

    (void)hipFuncSetAttribute((const void*)lstm_persistent,
                              hipFuncAttributeMaxDynamicSharedMemorySize, LDS_BYTES);

    lstm_persistent<<<dim3(256), dim3(512), LDS_BYTES, stream>>>(
        inputs, b, Wblob, Wdblob, bd, hbuf, flags, out, out_steps);
}